// Round 6
// baseline (782.519 us; speedup 1.0000x reference)
//
#include <hip/hip_runtime.h>
#include <stdint.h>

#define RDIM 14
#define CDIM 64
#define NFRAMES 4

// R5 (reg-slab + v_readlane broadcast, ~140us kernel) with the x-broadcast
// moved from the vector pipe to the scalar pipe. The x row address is
// wave-uniform, so uniform float4 loads compile to s_load_dwordx4 (2 rows =
// 112B = 7 aligned dwordx4); x values live in SGPRs and feed v_fma directly
// as the one-SGPR operand. Row body drops from ~28 VALU (14 readlane +
// 14 fma) to ~14 VALU -- VALU busy ~48us -> ~25us, freeing issue slots to
// keep the store stream saturated. ids prefetch, weight pinning, uniform
// 4-way branch, coalesced stores, grid: R5 verbatim.
constexpr int BLOCK = 256;
constexpr int WAVES_PER_BLOCK = BLOCK / 64;
constexpr int ROWS_PER_WAVE = 64;

__global__ __launch_bounds__(BLOCK, 4) void frame_proj_kernel(
    const float* __restrict__ X,      // (batch, 14)
    const int* __restrict__ ids,      // (batch,)
    const float* __restrict__ W,      // (4, 64, 14)
    const float* __restrict__ B,      // (4, 64)
    float* __restrict__ out,          // (batch, 64)
    int batch)
{
    const int lane = threadIdx.x & 63;
    const int wid  = __builtin_amdgcn_readfirstlane(threadIdx.x >> 6);
    const int gwid = blockIdx.x * WAVES_PER_BLOCK + wid;
    const int row0 = gwid * ROWS_PER_WAVE;
    if (row0 >= batch) return;

    // ---- per-lane weight cache (lane = output column), pinned in VGPRs ----
    float w[NFRAMES][RDIM];
    float bb[NFRAMES];
#pragma unroll
    for (int e = 0; e < NFRAMES; ++e) {
        const float2* wr = (const float2*)(W + (size_t)(e * CDIM + lane) * RDIM);
#pragma unroll
        for (int k = 0; k < 7; ++k) {
            float2 v = wr[k];
            w[e][2 * k]     = v.x;
            w[e][2 * k + 1] = v.y;
        }
        bb[e] = B[e * CDIM + lane];
    }
    // Pin: without this the compiler sinks weight loads into the row loop
    // (round-0 kernel: VGPR_Count=32, the cache never existed in registers).
#pragma unroll
    for (int e = 0; e < NFRAMES; ++e) {
#pragma unroll
        for (int k = 0; k < RDIM; ++k) asm volatile("" : "+v"(w[e][k]));
        asm volatile("" : "+v"(bb[e]));
    }

    auto dot = [&](const float (&xs)[RDIM], const float (&wk)[RDIM], float bias) {
        float a0 = bias, a1 = 0.0f;   // two chains halve dependent-FMA latency
#pragma unroll
        for (int k = 0; k < RDIM; k += 2) {
            a0 = fmaf(xs[k],     wk[k],     a0);
            a1 = fmaf(xs[k + 1], wk[k + 1], a1);
        }
        return a0 + a1;
    };

    auto sel = [&](const float (&xs)[RDIM], int id) {
        if (id == 0)      return dot(xs, w[0], bb[0]);   // wave-uniform branch
        else if (id == 1) return dot(xs, w[1], bb[1]);
        else if (id == 2) return dot(xs, w[2], bb[2]);
        else              return dot(xs, w[3], bb[3]);
    };

    if (row0 + ROWS_PER_WAVE <= batch) {
        // ---- fast path: ids in a VGPR, x rows via scalar loads ----
        const int idv = ids[row0 + lane];              // 256B coalesced, once
        float* orow = out + (size_t)row0 * CDIM + lane;

#pragma unroll
        for (int p = 0; p < ROWS_PER_WAVE / 2; ++p) {
            // Rows 2p,2p+1: 112B at a wave-uniform, 16B-aligned address
            // (row0*56 and 112*p are multiples of 16) -> 7x s_load_dwordx4.
            const float4* xp =
                (const float4*)(X + (size_t)(row0 + 2 * p) * RDIM);
            const float4 q0 = xp[0], q1 = xp[1], q2 = xp[2], q3 = xp[3];
            const float4 q4 = xp[4], q5 = xp[5], q6 = xp[6];

            const int id0 = __builtin_amdgcn_readlane(idv, 2 * p);
            const int id1 = __builtin_amdgcn_readlane(idv, 2 * p + 1);

            const float xa[RDIM] = { q0.x, q0.y, q0.z, q0.w,
                                     q1.x, q1.y, q1.z, q1.w,
                                     q2.x, q2.y, q2.z, q2.w,
                                     q3.x, q3.y };
            orow[(size_t)(2 * p) * CDIM] = sel(xa, id0);   // coalesced 256B

            const float xb[RDIM] = { q3.z, q3.w,
                                     q4.x, q4.y, q4.z, q4.w,
                                     q5.x, q5.y, q5.z, q5.w,
                                     q6.x, q6.y, q6.z, q6.w };
            orow[(size_t)(2 * p + 1) * CDIM] = sel(xb, id1);
        }
    } else {
        // ---- tail path (batch % 64 != 0 only; absent for 2M): uniform rows ----
        const int rend = batch - row0;
        for (int r = 0; r < rend; ++r) {
            const int id = __builtin_amdgcn_readfirstlane(ids[row0 + r]);
            const float2* xr2 = (const float2*)(X + (size_t)(row0 + r) * RDIM);
            float xs[RDIM];
#pragma unroll
            for (int k = 0; k < 7; ++k) {
                float2 v = xr2[k];
                xs[2 * k]     = v.x;
                xs[2 * k + 1] = v.y;
            }
            out[(size_t)(row0 + r) * CDIM + lane] = sel(xs, id);
        }
    }
}

extern "C" void kernel_launch(void* const* d_in, const int* in_sizes, int n_in,
                              void* d_out, int out_size, void* d_ws, size_t ws_size,
                              hipStream_t stream) {
    const float* X   = (const float*)d_in[0];
    const int*   ids = (const int*)d_in[1];
    const float* W   = (const float*)d_in[2];
    const float* B   = (const float*)d_in[3];
    float* out = (float*)d_out;

    const int batch = in_sizes[1];  // frame_type_ids element count

    const int rows_per_block = ROWS_PER_WAVE * WAVES_PER_BLOCK;  // 256
    const int grid = (batch + rows_per_block - 1) / rows_per_block;
    frame_proj_kernel<<<grid, BLOCK, 0, stream>>>(X, ids, W, B, out, batch);
}